// Round 1
// baseline (238.782 us; speedup 1.0000x reference)
//
#include <hip/hip_runtime.h>

#define POOL 7
#define IMG_H 256
#define IMG_W 256
#define IMG_C 512
#define NUM_ROIS 1024

// One block per (roi, cell). 128 threads × float4 = 512 channels.
__global__ __launch_bounds__(128) void roi_pool_kernel(
    const float* __restrict__ img,
    const int*   __restrict__ rois,
    float*       __restrict__ out)
{
    const int cell = blockIdx.x;          // 0..48
    const int roi  = blockIdx.y;          // 0..1023
    const int py = cell / POOL;
    const int px = cell - py * POOL;

    const int4 rb = ((const int4*)rois)[roi];
    const int x1 = rb.x, y1 = rb.y, x2 = rb.z, y2 = rb.w;

    // Match reference numerics: scale = h/P once, then py*scale.
    const float h = (float)(y2 - y1);
    const float w = (float)(x2 - x1);
    const float ys = (float)py * (h * (1.0f / POOL));
    const float xs = (float)px * (w * (1.0f / POOL));
    const int y0 = (int)floorf(ys);
    const int x0 = (int)floorf(xs);
    const int y1i = min(y0 + 1, max(y2 - y1 - 1, 0));
    const int x1i = min(x0 + 1, max(x2 - x1 - 1, 0));
    const float wy = ys - (float)y0;
    const float wx = xs - (float)x0;

    const int r0 = y1 + y0,  r1 = y1 + y1i;
    const int c0 = x1 + x0,  c1 = x1 + x1i;

    const float w00 = (1.0f - wy) * (1.0f - wx);
    const float w01 = (1.0f - wy) * wx;
    const float w10 = wy * (1.0f - wx);
    const float w11 = wy * wx;

    const float4* p00 = (const float4*)(img + ((size_t)r0 * IMG_W + c0) * IMG_C);
    const float4* p01 = (const float4*)(img + ((size_t)r0 * IMG_W + c1) * IMG_C);
    const float4* p10 = (const float4*)(img + ((size_t)r1 * IMG_W + c0) * IMG_C);
    const float4* p11 = (const float4*)(img + ((size_t)r1 * IMG_W + c1) * IMG_C);
    float4* po = (float4*)(out + (((size_t)roi * POOL + py) * POOL + px) * IMG_C);

    const int t = threadIdx.x;            // 0..127 covers 512 channels as float4
    const float4 v00 = p00[t];
    const float4 v01 = p01[t];
    const float4 v10 = p10[t];
    const float4 v11 = p11[t];

    float4 o;
    o.x = v00.x * w00 + v01.x * w01 + v10.x * w10 + v11.x * w11;
    o.y = v00.y * w00 + v01.y * w01 + v10.y * w10 + v11.y * w11;
    o.z = v00.z * w00 + v01.z * w01 + v10.z * w10 + v11.z * w11;
    o.w = v00.w * w00 + v01.w * w01 + v10.w * w10 + v11.w * w11;
    po[t] = o;
}

extern "C" void kernel_launch(void* const* d_in, const int* in_sizes, int n_in,
                              void* d_out, int out_size, void* d_ws, size_t ws_size,
                              hipStream_t stream) {
    const float* img  = (const float*)d_in[0];
    const int*   rois = (const int*)d_in[1];
    float* out = (float*)d_out;

    dim3 grid(POOL * POOL, NUM_ROIS);
    dim3 block(128);
    roi_pool_kernel<<<grid, block, 0, stream>>>(img, rois, out);
}

// Round 2
// 236.520 us; speedup vs baseline: 1.0096x; 1.0096x over previous
//
#include <hip/hip_runtime.h>

#define POOL 7
#define IMG_W 256
#define IMG_C 512
#define NUM_ROIS 1024

typedef float f4 __attribute__((ext_vector_type(4)));

// One block per (roi, py): loops px=0..6 fully unrolled.
// 128 threads x float4 = 512 channels.
// Block-id swizzle: assuming round-robin block->XCD (bid % 8), each XCD gets
// 128 contiguous ROIs so intra-ROI pixel reuse stays in that XCD's 4MB L2.
__global__ __launch_bounds__(128) void roi_pool_kernel(
    const float* __restrict__ img,
    const int*   __restrict__ rois,
    float*       __restrict__ out)
{
    const int bid  = blockIdx.x;          // 0..7167
    const int xcd  = bid & 7;
    const int slot = bid >> 3;            // 0..895
    const int rloc = slot / POOL;         // 0..127
    const int py   = slot - rloc * POOL;  // 0..6
    const int roi  = xcd * (NUM_ROIS / 8) + rloc;

    const int4 rb = ((const int4*)rois)[roi];
    // Force wave-uniform values into SGPRs: address math goes scalar.
    const int x1 = __builtin_amdgcn_readfirstlane(rb.x);
    const int y1 = __builtin_amdgcn_readfirstlane(rb.y);
    const int x2 = __builtin_amdgcn_readfirstlane(rb.z);
    const int y2 = __builtin_amdgcn_readfirstlane(rb.w);

    const float h = (float)(y2 - y1);
    const float w = (float)(x2 - x1);
    const float sy = h / (float)POOL;     // match reference: h/P then py*(h/P)
    const float sx = w / (float)POOL;

    const float ys = (float)py * sy;
    const int   y0 = (int)floorf(ys);
    const int   y1i = min(y0 + 1, max(y2 - y1 - 1, 0));
    const float wy = ys - (float)y0;

    const size_t rowstride = (size_t)IMG_W * IMG_C;
    const float* row0 = img + (size_t)(y1 + y0)  * rowstride;
    const float* row1 = img + (size_t)(y1 + y1i) * rowstride;

    const int t = threadIdx.x;            // 0..127
    f4* obase = (f4*)out + ((size_t)roi * (POOL * POOL) + (size_t)py * POOL) * (IMG_C / 4) + t;

    const int cmax = max(x2 - x1 - 1, 0);

#pragma unroll
    for (int px = 0; px < POOL; ++px) {
        const float xs = (float)px * sx;
        const int   x0 = (int)floorf(xs);
        const int   x1i = min(x0 + 1, cmax);
        const float wx = xs - (float)x0;
        const int c0 = x1 + x0, c1 = x1 + x1i;

        const f4 v00 = ((const f4*)(row0 + (size_t)c0 * IMG_C))[t];
        const f4 v01 = ((const f4*)(row0 + (size_t)c1 * IMG_C))[t];
        const f4 v10 = ((const f4*)(row1 + (size_t)c0 * IMG_C))[t];
        const f4 v11 = ((const f4*)(row1 + (size_t)c1 * IMG_C))[t];

        const float w00 = (1.0f - wy) * (1.0f - wx);
        const float w01 = (1.0f - wy) * wx;
        const float w10 = wy * (1.0f - wx);
        const float w11 = wy * wx;

        f4 o = v00 * w00 + v01 * w01 + v10 * w10 + v11 * w11;
        // Output is write-once: bypass L2 so the 100MB store stream doesn't
        // evict image lines.
        __builtin_nontemporal_store(o, obase + px * (IMG_C / 4));
    }
}

extern "C" void kernel_launch(void* const* d_in, const int* in_sizes, int n_in,
                              void* d_out, int out_size, void* d_ws, size_t ws_size,
                              hipStream_t stream) {
    const float* img  = (const float*)d_in[0];
    const int*   rois = (const int*)d_in[1];
    float* out = (float*)d_out;

    dim3 grid(NUM_ROIS * POOL);   // 7168 blocks = (roi, py)
    dim3 block(128);
    roi_pool_kernel<<<grid, block, 0, stream>>>(img, rois, out);
}